// Round 11
// baseline (158.492 us; speedup 1.0000x reference)
//
#include <hip/hip_runtime.h>

#define IX 1440
#define IY 720
#define NB 4
#define PLANE (IY * IX)            // 1,036,800
#define NOUT (NB * 12 * PLANE)     // 49,766,400
#define NTHREADS (NB * PLANE / 2)  // 2,073,600 threads, 2 px each
#define NWG (NTHREADS / 256)       // 8100
#define SWZ_Q (NWG / 8)            // 1012
#define SWZ_R (NWG % 8)            // 4

typedef float f2v __attribute__((ext_vector_type(2)));
typedef float f4v __attribute__((ext_vector_type(4)));

__device__ __forceinline__ void ld2(const float* p, float* o) {
    const f2v v = *reinterpret_cast<const f2v*>(p);
    o[0] = v.x; o[1] = v.y;
}

__global__ __launch_bounds__(256) void euler_kernel(
    const float* __restrict__ Field,
    const float* __restrict__ W,
    const float* __restrict__ bvec,
    const float* __restrict__ thermal,
    float* __restrict__ out,
    float* __restrict__ part)          // per-block partials: part[bid*4 + i]
{
    __shared__ float sW[180];
    __shared__ float sB[16];
    __shared__ float sRed[4][4];

    const int t = threadIdx.x;
    if (t < 180) sW[t] = W[t];
    if (t < 15)  sB[t] = bvec[t];
    const float th = thermal[0];
    __syncthreads();

    // bijective XCD-slab swizzle (m204)
    const int bid = blockIdx.x;
    const int xcd = bid & 7, pos = bid >> 3;
    const int wg  = (xcd < SWZ_R ? xcd * (SWZ_Q + 1)
                                 : SWZ_R * (SWZ_Q + 1) + (xcd - SWZ_R) * SWZ_Q) + pos;

    const int tid = wg * 256 + t;
    const int xi  = tid % 720;          // which float2 in the row
    const int row = tid / 720;          // global (b,y) row
    const int x2  = xi * 2;
    const int y   = row % IY;
    const int b   = row / IY;

    const int xm  = (x2 == 0)      ? IX - 2 : x2 - 2;
    const int xp  = (x2 == IX - 2) ? 0      : x2 + 2;
    const int ym1 = (y == 0)      ? IY - 1       : y - 1;
    const int ym2 = (y < 2)       ? y + IY - 2   : y - 2;
    const int yp1 = (y == IY - 1) ? 0            : y + 1;
    const int yp2 = (y >= IY - 2) ? y - (IY - 2) : y + 2;

    const float* base = Field + (size_t)b * 12 * PLANE;
    const size_t ro = (size_t)y * IX;
    const size_t om2 = (size_t)ym2 * IX + x2;
    const size_t om1 = (size_t)ym1 * IX + x2;
    const size_t op1 = (size_t)yp1 * IX + x2;
    const size_t op2 = (size_t)yp2 * IX + x2;

    // center values, all 12 channels (batched independent loads)
    float ctr[12][2];
#pragma unroll
    for (int c = 0; c < 12; ++c) ld2(base + (size_t)c * PLANE + ro + x2, ctr[c]);

    // ml[12..14] ("o") — needed by every physics term
    float ml12[3][2];
#pragma unroll
    for (int z = 0; z < 3; ++z) {
#pragma unroll
        for (int j = 0; j < 2; ++j) ml12[z][j] = sB[12 + z];
#pragma unroll
        for (int cc = 0; cc < 12; ++cc) {
            const float wv = sW[(12 + z) * 12 + cc];
#pragma unroll
            for (int j = 0; j < 2; ++j) ml12[z][j] = fmaf(wv, ctr[cc][j], ml12[z][j]);
        }
    }

    float c2 = 0.f, ef2 = 0.f, pp2 = 0.f, xy2 = 0.f;
    float* ob = out + (size_t)b * 12 * PLANE + ro + x2;

#pragma unroll
    for (int z = 0; z < 3; ++z) {
        const int zp = (z == 2) ? 0 : z + 1;
        const int zm = (z == 0) ? 2 : z - 1;
        const float invp = (z == 0) ? 0.1f : (z == 1) ? (1.0f / 8.5f) : 0.2f;

        // batch-issue ALL 24 halo loads for this z-group (4 channels × 6 f2v)
        float hx[4][12];
#pragma unroll
        for (int f = 0; f < 4; ++f) {
            const float* pc = base + (size_t)(f * 3 + z) * PLANE;
            ld2(pc + ro + xm, &hx[f][0]);
            ld2(pc + ro + xp, &hx[f][2]);
            ld2(pc + om2,     &hx[f][4]);
            ld2(pc + om1,     &hx[f][6]);
            ld2(pc + op1,     &hx[f][8]);
            ld2(pc + op2,     &hx[f][10]);
        }
        __builtin_amdgcn_sched_barrier(0);   // keep the load batch above the consumers

        float fdx9[2], fdy9[2], conz[2];

#pragma unroll
        for (int fi = 0; fi < 4; ++fi) {
            const int f = (fi == 0) ? 3 : fi - 1;   // 3,0,1,2
            const int c = f * 3 + z;
            const float* h = hx[f];

            float fdx[2], fdy[2];
            fdx[0] = (h[0] - h[2] + 8.0f * (ctr[c][1] - h[1])) * (1.0f / 12.0f);
            fdx[1] = (h[1] - h[3] + 8.0f * (h[2] - ctr[c][0])) * (1.0f / 12.0f);
#pragma unroll
            for (int j = 0; j < 2; ++j)
                fdy[j] = (h[4 + j] - h[10 + j] + 8.0f * (h[8 + j] - h[6 + j])) * (1.0f / 12.0f);

            float mlc[2];
#pragma unroll
            for (int j = 0; j < 2; ++j) mlc[j] = sB[c];
#pragma unroll
            for (int cc = 0; cc < 12; ++cc) {
                const float wv = sW[c * 12 + cc];
#pragma unroll
                for (int j = 0; j < 2; ++j) mlc[j] = fmaf(wv, ctr[cc][j], mlc[j]);
            }

            if (f == 3) {   // first in group: stash fdx9/fdy9, init conz
#pragma unroll
                for (int j = 0; j < 2; ++j) {
                    fdx9[j] = fdx[j]; fdy9[j] = fdy[j];
                    conz[j] = 0.5f * (ml12[zp][j] - ml12[zm][j]);
                }
            }
            if (f == 0) {
#pragma unroll
                for (int j = 0; j < 2; ++j) conz[j] += fdx[j];
            }
            if (f == 1) {
#pragma unroll
                for (int j = 0; j < 2; ++j) conz[j] += fdy[j];
            }

            float st[2];
#pragma unroll
            for (int j = 0; j < 2; ++j) {
                const float fdz = 0.5f * (ctr[f * 3 + zp][j] - ctr[f * 3 + zm][j]);
                const float xyd = -ctr[z][j] * fdx[j] - ctr[3 + z][j] * fdy[j];
                float ph;
                if      (f == 0) ph = -fdx9[j];
                else if (f == 1) ph = -fdy9[j];
                else if (f == 2) ph = th * ctr[6 + z][j] * invp * ml12[z][j];
                else             ph = 0.0f;
                const float phys = xyd - ml12[z][j] * fdz + ph;
                st[j] = ctr[c][j] + mlc[j] + phys;
                ef2 = fmaf(mlc[j], mlc[j], ef2);
                pp2 = fmaf(phys,   phys,   pp2);
                xy2 = fmaf(xyd,    xyd,    xy2);
            }
            // A/B vs R10: plain store (NT removed — single-variable test)
            f2v sv; sv.x = st[0]; sv.y = st[1];
            *reinterpret_cast<f2v*>(ob + (size_t)c * PLANE) = sv;
        }

#pragma unroll
        for (int j = 0; j < 2; ++j) c2 = fmaf(conz[j], conz[j], c2);
    }

    // block reduction of the 4 partial sums → plain store (NO atomics)
    float vals[4] = { c2, ef2, pp2, xy2 };
    const int lane = t & 63;
    const int wv   = t >> 6;
#pragma unroll
    for (int i = 0; i < 4; ++i) {
        float v = vals[i];
        for (int off = 32; off > 0; off >>= 1) v += __shfl_down(v, off, 64);
        if (lane == 0) sRed[wv][i] = v;
    }
    __syncthreads();
    if (t < 4) {
        part[bid * 4 + t] = sRed[0][t] + sRed[1][t] + sRed[2][t] + sRed[3][t];
    }
}

__global__ __launch_bounds__(256) void finalize_kernel(
    const float* __restrict__ part, float* __restrict__ out)
{
    __shared__ double sAcc[4][4];   // [wave][metric]
    const int t = threadIdx.x;
    double a0 = 0.0, a1 = 0.0, a2 = 0.0, a3 = 0.0;
    for (int i = t; i < NWG; i += 256) {
        const f4v v = *reinterpret_cast<const f4v*>(&part[i * 4]);
        a0 += (double)v.x; a1 += (double)v.y; a2 += (double)v.z; a3 += (double)v.w;
    }
    // wave reduce (64 lanes)
    const int lane = t & 63, wv = t >> 6;
    for (int off = 32; off > 0; off >>= 1) {
        a0 += __shfl_down(a0, off, 64);
        a1 += __shfl_down(a1, off, 64);
        a2 += __shfl_down(a2, off, 64);
        a3 += __shfl_down(a3, off, 64);
    }
    if (lane == 0) { sAcc[wv][0] = a0; sAcc[wv][1] = a1; sAcc[wv][2] = a2; sAcc[wv][3] = a3; }
    __syncthreads();
    if (t == 0) {
        const double s0 = sAcc[0][0] + sAcc[1][0] + sAcc[2][0] + sAcc[3][0];
        const double s1 = sAcc[0][1] + sAcc[1][1] + sAcc[2][1] + sAcc[3][1];
        const double s2 = sAcc[0][2] + sAcc[1][2] + sAcc[2][2] + sAcc[3][2];
        const double s3 = sAcc[0][3] + sAcc[1][3] + sAcc[2][3] + sAcc[3][3];
        out[NOUT + 0] = (float)(s0 / (double)(NB * 3 * PLANE));  // mean(constrain^2)
        out[NOUT + 1] = (float)(s1 / (double)NOUT);              // mean(ExternalForce^2)
        out[NOUT + 2] = (float)(s2 / (double)NOUT);              // mean(PhysicsPart^2)
        out[NOUT + 3] = (float)(s3 / (double)NOUT);              // mean(xydirection^2)
    }
}

extern "C" void kernel_launch(void* const* d_in, const int* in_sizes, int n_in,
                              void* d_out, int out_size, void* d_ws, size_t ws_size,
                              hipStream_t stream) {
    const float* Field   = (const float*)d_in[0];
    const float* W       = (const float*)d_in[1];
    const float* bvec    = (const float*)d_in[2];
    const float* thermal = (const float*)d_in[3];
    float* out  = (float*)d_out;
    float* part = (float*)d_ws;     // 8100 * 4 floats = 129.6 KB

    euler_kernel<<<NWG, 256, 0, stream>>>(Field, W, bvec, thermal, out, part);
    finalize_kernel<<<1, 256, 0, stream>>>(part, out);
}

// Round 12
// 115.080 us; speedup vs baseline: 1.3772x; 1.3772x over previous
//
#include <hip/hip_runtime.h>

#define IX 1440
#define IY 720
#define NB 4
#define PLANE (IY * IX)            // 1,036,800
#define NOUT (NB * 12 * PLANE)     // 49,766,400
#define NTHREADS (NB * PLANE / 2)  // 2,073,600 threads, 2 px each
#define NWG (NTHREADS / 256)       // 8100
#define SWZ_Q (NWG / 8)            // 1012
#define SWZ_R (NWG % 8)            // 4

typedef float f2v __attribute__((ext_vector_type(2)));
typedef float f4v __attribute__((ext_vector_type(4)));

__device__ __forceinline__ void ld2(const float* p, float* o) {
    const f2v v = *reinterpret_cast<const f2v*>(p);
    o[0] = v.x; o[1] = v.y;
}

// one channel's stencil+matvec+store; F,Z compile-time so all branches fold
template<int F, int Z>
__device__ __forceinline__ void stepF(
    const float ctr[12][2], const float ml12[3][2], const float* h,
    const float* sW, const float* sB, float th,
    float* fdx9, float* fdy9, float* conz, float* ob,
    float& ef2, float& pp2, float& xy2)
{
    constexpr int C  = F * 3 + Z;
    constexpr int ZP = (Z == 2) ? 0 : Z + 1;
    constexpr int ZM = (Z == 0) ? 2 : Z - 1;
    const float invp = (Z == 0) ? 0.1f : (Z == 1) ? (1.0f / 8.5f) : 0.2f;

    float fdx[2], fdy[2];
    fdx[0] = (h[0] - h[2] + 8.0f * (ctr[C][1] - h[1])) * (1.0f / 12.0f);
    fdx[1] = (h[1] - h[3] + 8.0f * (h[2] - ctr[C][0])) * (1.0f / 12.0f);
    fdy[0] = (h[4] - h[10] + 8.0f * (h[8] - h[6])) * (1.0f / 12.0f);
    fdy[1] = (h[5] - h[11] + 8.0f * (h[9] - h[7])) * (1.0f / 12.0f);

    float mlc[2];
#pragma unroll
    for (int j = 0; j < 2; ++j) mlc[j] = sB[C];
#pragma unroll
    for (int cc = 0; cc < 12; ++cc) {
        const float wv = sW[C * 12 + cc];
#pragma unroll
        for (int j = 0; j < 2; ++j) mlc[j] = fmaf(wv, ctr[cc][j], mlc[j]);
    }

    if constexpr (F == 3) {
#pragma unroll
        for (int j = 0; j < 2; ++j) {
            fdx9[j] = fdx[j]; fdy9[j] = fdy[j];
            conz[j] = 0.5f * (ml12[ZP][j] - ml12[ZM][j]);
        }
    }
    if constexpr (F == 0) {
#pragma unroll
        for (int j = 0; j < 2; ++j) conz[j] += fdx[j];
    }
    if constexpr (F == 1) {
#pragma unroll
        for (int j = 0; j < 2; ++j) conz[j] += fdy[j];
    }

    float st[2];
#pragma unroll
    for (int j = 0; j < 2; ++j) {
        const float fdz = 0.5f * (ctr[F * 3 + ZP][j] - ctr[F * 3 + ZM][j]);
        const float xyd = -ctr[Z][j] * fdx[j] - ctr[3 + Z][j] * fdy[j];
        float ph;
        if constexpr (F == 0)      ph = -fdx9[j];
        else if constexpr (F == 1) ph = -fdy9[j];
        else if constexpr (F == 2) ph = th * ctr[6 + Z][j] * invp * ml12[Z][j];
        else                       ph = 0.0f;
        const float phys = xyd - ml12[Z][j] * fdz + ph;
        st[j] = ctr[C][j] + mlc[j] + phys;
        ef2 = fmaf(mlc[j], mlc[j], ef2);
        pp2 = fmaf(phys,   phys,   pp2);
        xy2 = fmaf(xyd,    xyd,    xy2);
    }
    f2v sv; sv.x = st[0]; sv.y = st[1];
    __builtin_nontemporal_store(sv, reinterpret_cast<f2v*>(ob + (size_t)C * PLANE));
}

__global__ __launch_bounds__(256) void euler_kernel(
    const float* __restrict__ Field,
    const float* __restrict__ W,
    const float* __restrict__ bvec,
    const float* __restrict__ thermal,
    float* __restrict__ out,
    float* __restrict__ part)
{
    __shared__ float sW[180];
    __shared__ float sB[16];
    __shared__ float sRed[4][4];

    const int t = threadIdx.x;
    if (t < 180) sW[t] = W[t];
    if (t < 15)  sB[t] = bvec[t];
    const float th = thermal[0];
    __syncthreads();

    // bijective XCD-slab swizzle (m204)
    const int bid = blockIdx.x;
    const int xcd = bid & 7, pos = bid >> 3;
    const int wg  = (xcd < SWZ_R ? xcd * (SWZ_Q + 1)
                                 : SWZ_R * (SWZ_Q + 1) + (xcd - SWZ_R) * SWZ_Q) + pos;

    const int tid = wg * 256 + t;
    const int xi  = tid % 720;
    const int row = tid / 720;
    const int x2  = xi * 2;
    const int y   = row % IY;
    const int b   = row / IY;

    const int xm  = (x2 == 0)      ? IX - 2 : x2 - 2;
    const int xp  = (x2 == IX - 2) ? 0      : x2 + 2;
    const int ym1 = (y == 0)      ? IY - 1       : y - 1;
    const int ym2 = (y < 2)       ? y + IY - 2   : y - 2;
    const int yp1 = (y == IY - 1) ? 0            : y + 1;
    const int yp2 = (y >= IY - 2) ? y - (IY - 2) : y + 2;

    const float* base = Field + (size_t)b * 12 * PLANE;
    // 32-bit offsets (max < 2^31) to hold VGPR down
    const int ro  = y * IX;
    const int oxm = ro + xm, oxp = ro + xp;
    const int om2 = ym2 * IX + x2, om1 = ym1 * IX + x2;
    const int op1 = yp1 * IX + x2, op2 = yp2 * IX + x2;

    // halo issue: 6 f2v loads for channel c, in consume-order positions
    auto issueC = [&](int c, float* h) {
        const float* pc = base + (size_t)c * PLANE;
        ld2(pc + oxm, h + 0);
        ld2(pc + oxp, h + 2);
        ld2(pc + om2, h + 4);
        ld2(pc + om1, h + 6);
        ld2(pc + op1, h + 8);
        ld2(pc + op2, h + 10);
    };

    // ---- prologue: issue ctr (12) then z=0 halos in consume order (f=3,0,1,2)
    float ctr[12][2];
#pragma unroll
    for (int c = 0; c < 12; ++c) ld2(base + (size_t)c * PLANE + ro + x2, ctr[c]);

    float h3[12], h0[12], h1[12], h2[12];
    issueC(9, h3); issueC(0, h0); issueC(3, h1); issueC(6, h2);
    __builtin_amdgcn_sched_barrier(0);

    // ml12 waits only on ctr (vmcnt(24)); halos keep flying underneath
    float ml12[3][2];
#pragma unroll
    for (int z = 0; z < 3; ++z) {
#pragma unroll
        for (int j = 0; j < 2; ++j) ml12[z][j] = sB[12 + z];
#pragma unroll
        for (int cc = 0; cc < 12; ++cc) {
            const float wv = sW[(12 + z) * 12 + cc];
#pragma unroll
            for (int j = 0; j < 2; ++j) ml12[z][j] = fmaf(wv, ctr[cc][j], ml12[z][j]);
        }
    }

    float c2 = 0.f, ef2 = 0.f, pp2 = 0.f, xy2 = 0.f;
    float* ob = out + (size_t)b * 12 * PLANE + ro + x2;
    float fdx9[2], fdy9[2], conz[2];

    // ================= z = 0 =================
    stepF<3, 0>(ctr, ml12, h3, sW, sB, th, fdx9, fdy9, conz, ob, ef2, pp2, xy2);
    issueC(10, h3);                          // prefetch z=1 f=3 into dead h3
    __builtin_amdgcn_sched_barrier(0);
    stepF<0, 0>(ctr, ml12, h0, sW, sB, th, fdx9, fdy9, conz, ob, ef2, pp2, xy2);
    stepF<1, 0>(ctr, ml12, h1, sW, sB, th, fdx9, fdy9, conz, ob, ef2, pp2, xy2);
    stepF<2, 0>(ctr, ml12, h2, sW, sB, th, fdx9, fdy9, conz, ob, ef2, pp2, xy2);
    issueC(1, h0); issueC(4, h1); issueC(7, h2);   // z=1 f=0,1,2
    __builtin_amdgcn_sched_barrier(0);
    c2 = fmaf(conz[0], conz[0], c2); c2 = fmaf(conz[1], conz[1], c2);

    // ================= z = 1 =================
    stepF<3, 1>(ctr, ml12, h3, sW, sB, th, fdx9, fdy9, conz, ob, ef2, pp2, xy2);
    issueC(11, h3);                          // prefetch z=2 f=3
    __builtin_amdgcn_sched_barrier(0);
    stepF<0, 1>(ctr, ml12, h0, sW, sB, th, fdx9, fdy9, conz, ob, ef2, pp2, xy2);
    stepF<1, 1>(ctr, ml12, h1, sW, sB, th, fdx9, fdy9, conz, ob, ef2, pp2, xy2);
    stepF<2, 1>(ctr, ml12, h2, sW, sB, th, fdx9, fdy9, conz, ob, ef2, pp2, xy2);
    issueC(2, h0); issueC(5, h1); issueC(8, h2);   // z=2 f=0,1,2
    __builtin_amdgcn_sched_barrier(0);
    c2 = fmaf(conz[0], conz[0], c2); c2 = fmaf(conz[1], conz[1], c2);

    // ================= z = 2 =================
    stepF<3, 2>(ctr, ml12, h3, sW, sB, th, fdx9, fdy9, conz, ob, ef2, pp2, xy2);
    stepF<0, 2>(ctr, ml12, h0, sW, sB, th, fdx9, fdy9, conz, ob, ef2, pp2, xy2);
    stepF<1, 2>(ctr, ml12, h1, sW, sB, th, fdx9, fdy9, conz, ob, ef2, pp2, xy2);
    stepF<2, 2>(ctr, ml12, h2, sW, sB, th, fdx9, fdy9, conz, ob, ef2, pp2, xy2);
    c2 = fmaf(conz[0], conz[0], c2); c2 = fmaf(conz[1], conz[1], c2);

    // block reduction of the 4 partial sums → plain store (NO atomics)
    float vals[4] = { c2, ef2, pp2, xy2 };
    const int lane = t & 63;
    const int wv   = t >> 6;
#pragma unroll
    for (int i = 0; i < 4; ++i) {
        float v = vals[i];
        for (int off = 32; off > 0; off >>= 1) v += __shfl_down(v, off, 64);
        if (lane == 0) sRed[wv][i] = v;
    }
    __syncthreads();
    if (t < 4) {
        part[bid * 4 + t] = sRed[0][t] + sRed[1][t] + sRed[2][t] + sRed[3][t];
    }
}

__global__ __launch_bounds__(256) void finalize_kernel(
    const float* __restrict__ part, float* __restrict__ out)
{
    __shared__ double sAcc[4][4];
    const int t = threadIdx.x;
    double a0 = 0.0, a1 = 0.0, a2 = 0.0, a3 = 0.0;
    for (int i = t; i < NWG; i += 256) {
        const f4v v = *reinterpret_cast<const f4v*>(&part[i * 4]);
        a0 += (double)v.x; a1 += (double)v.y; a2 += (double)v.z; a3 += (double)v.w;
    }
    const int lane = t & 63, wv = t >> 6;
    for (int off = 32; off > 0; off >>= 1) {
        a0 += __shfl_down(a0, off, 64);
        a1 += __shfl_down(a1, off, 64);
        a2 += __shfl_down(a2, off, 64);
        a3 += __shfl_down(a3, off, 64);
    }
    if (lane == 0) { sAcc[wv][0] = a0; sAcc[wv][1] = a1; sAcc[wv][2] = a2; sAcc[wv][3] = a3; }
    __syncthreads();
    if (t == 0) {
        const double s0 = sAcc[0][0] + sAcc[1][0] + sAcc[2][0] + sAcc[3][0];
        const double s1 = sAcc[0][1] + sAcc[1][1] + sAcc[2][1] + sAcc[3][1];
        const double s2 = sAcc[0][2] + sAcc[1][2] + sAcc[2][2] + sAcc[3][2];
        const double s3 = sAcc[0][3] + sAcc[1][3] + sAcc[2][3] + sAcc[3][3];
        out[NOUT + 0] = (float)(s0 / (double)(NB * 3 * PLANE));
        out[NOUT + 1] = (float)(s1 / (double)NOUT);
        out[NOUT + 2] = (float)(s2 / (double)NOUT);
        out[NOUT + 3] = (float)(s3 / (double)NOUT);
    }
}

extern "C" void kernel_launch(void* const* d_in, const int* in_sizes, int n_in,
                              void* d_out, int out_size, void* d_ws, size_t ws_size,
                              hipStream_t stream) {
    const float* Field   = (const float*)d_in[0];
    const float* W       = (const float*)d_in[1];
    const float* bvec    = (const float*)d_in[2];
    const float* thermal = (const float*)d_in[3];
    float* out  = (float*)d_out;
    float* part = (float*)d_ws;     // 8100 * 4 floats = 129.6 KB

    euler_kernel<<<NWG, 256, 0, stream>>>(Field, W, bvec, thermal, out, part);
    finalize_kernel<<<1, 256, 0, stream>>>(part, out);
}